// Round 4
// baseline (117.147 us; speedup 1.0000x reference)
//
#include <hip/hip_runtime.h>

// Problem constants (fixed by setup_inputs)
#define BB 4
#define SS 2048
#define HH 4096
#define KVH 8
#define DD 128
#define MAXSEQ 4096
#define RANK 64
#define HDN 1024   // H/4
#define W1ROWS (HH + 2)

typedef float f4 __attribute__((ext_vector_type(4)));   // nontemporal-friendly

// Workspace layout (float slots):
//   [0, 16384)        pooled sums  (B*H)
//   [16384, 20480)    hdn          (B*HDN)
//   [20480, 20488)    strat        (B*2)
//   20488             counter (int)
//   [20492, 22540)    inv (int[SS])
#define WS_POOLED 0
#define WS_HDN    16384
#define WS_STRAT  20480
#define WS_CNT    20488
#define WS_INV    20492

__global__ void init_ws_kernel(float* __restrict__ wsf) {
    int idx = blockIdx.x * 256 + threadIdx.x;
    if (idx < WS_STRAT) wsf[idx] = 0.0f;           // pooled + hdn
    if (idx == WS_CNT) ((int*)wsf)[WS_CNT] = 0;    // ticket counter
    int j = idx - WS_INV;
    if (j >= 0 && j < SS) ((int*)wsf)[WS_INV + j] = -1;
}

// Fused: pooled partial sums (nt f4 loads, atomics) + scatter-inverse map.
// grid = B * 128 * 4 = 2048 blocks, 256 threads. 16 rows x 1024 ch per block.
__global__ void pool_scatter_kernel(const float* __restrict__ hidden,
                                    const int* __restrict__ cache_position,
                                    float* __restrict__ pooled,
                                    int* __restrict__ inv) {
    if (blockIdx.x < (SS / 256)) {
        int i = blockIdx.x * 256 + threadIdx.x;
        int pos = cache_position[i];
        if (pos >= 0 && pos < SS) atomicMax(&inv[pos], i);  // last-wins
    }
    int blk = blockIdx.x;
    int cblk = blk & 3;   blk >>= 2;
    int sch  = blk & 127; blk >>= 7;
    int b = blk;
    int c0 = cblk * 1024 + threadIdx.x * 4;
    const float* base = hidden + (size_t)b * SS * HH + (size_t)sch * 16 * HH + c0;
    f4 acc = (f4)(0.f);
    #pragma unroll
    for (int s = 0; s < 16; ++s) {
        f4 v = __builtin_nontemporal_load((const f4*)(base + (size_t)s * HH));
        acc += v;
    }
    float* p = pooled + b * HH + c0;
    atomicAdd(p + 0, acc.x);
    atomicAdd(p + 1, acc.y);
    atomicAdd(p + 2, acc.z);
    atomicAdd(p + 3, acc.w);
}

// GEMV feats @ w1 over 64-row k-chunks (65 blocks), atomics into hdn.
// Last-finishing block computes mlp2 (relu -> @w2 -> softmax -> strat) inline.
__global__ void mlp_kernel(const float* __restrict__ pooled,
                           const float* __restrict__ w1,
                           const float* __restrict__ b1,
                           const float* __restrict__ w2,
                           const float* __restrict__ b2,
                           const int* __restrict__ layer_idx,
                           float* __restrict__ hdn,
                           int* __restrict__ counter,
                           float* __restrict__ strat) {
    int t = threadIdx.x;
    int j0 = t * 4;
    const float inv_s = 1.0f / (float)SS;
    int k0 = blockIdx.x * 64;
    int kend = min(k0 + 64, W1ROWS);
    f4 acc[BB];
    #pragma unroll
    for (int b = 0; b < BB; ++b) acc[b] = (f4)(0.f);
    for (int k = k0; k < kend; ++k) {
        f4 w = __builtin_nontemporal_load((const f4*)(w1 + (size_t)k * HDN + j0));
        float f[BB];
        if (k < HH) {
            #pragma unroll
            for (int b = 0; b < BB; ++b) f[b] = pooled[b * HH + k] * inv_s;
        } else if (k == HH) {
            float li = (float)(*layer_idx);
            #pragma unroll
            for (int b = 0; b < BB; ++b) f[b] = li;
        } else {
            #pragma unroll
            for (int b = 0; b < BB; ++b) f[b] = (float)SS;
        }
        #pragma unroll
        for (int b = 0; b < BB; ++b) acc[b] += f[b] * w;
    }
    #pragma unroll
    for (int b = 0; b < BB; ++b) {
        float* h = hdn + b * HDN + j0;
        atomicAdd(h + 0, acc[b].x);
        atomicAdd(h + 1, acc[b].y);
        atomicAdd(h + 2, acc[b].z);
        atomicAdd(h + 3, acc[b].w);
    }

    // ---- last-block-done detection ----
    __shared__ int sTicket;
    __threadfence();            // make this block's atomics globally ordered
    __syncthreads();            // all threads' atomics issued+fenced
    if (t == 0) sTicket = atomicAdd(counter, 1);
    __syncthreads();
    if (sTicket != (int)gridDim.x - 1) return;
    __threadfence();            // acquire: see all other blocks' hdn atomics

    // ---- mlp2 on the last block (256 threads, each owns 4 j) ----
    __shared__ float wred[4][16];
    __shared__ float logits[16];
    float l[BB][4];
    #pragma unroll
    for (int b = 0; b < BB; ++b)
        #pragma unroll
        for (int m = 0; m < 4; ++m) l[b][m] = 0.f;
    #pragma unroll
    for (int jj = 0; jj < 4; ++jj) {
        int j = j0 + jj;
        float bias = b1[j];
        f4 w2v = *(const f4*)(w2 + j * 4);
        #pragma unroll
        for (int b = 0; b < BB; ++b) {
            float h = hdn[b * HDN + j] + bias;
            h = h > 0.f ? h : 0.f;
            l[b][0] = fmaf(h, w2v.x, l[b][0]);
            l[b][1] = fmaf(h, w2v.y, l[b][1]);
            l[b][2] = fmaf(h, w2v.z, l[b][2]);
            l[b][3] = fmaf(h, w2v.w, l[b][3]);
        }
    }
    int wave = t >> 6, lane = t & 63;
    #pragma unroll
    for (int off = 32; off > 0; off >>= 1)
        #pragma unroll
        for (int b = 0; b < BB; ++b)
            #pragma unroll
            for (int m = 0; m < 4; ++m)
                l[b][m] += __shfl_down(l[b][m], off, 64);
    if (lane == 0)
        #pragma unroll
        for (int b = 0; b < BB; ++b)
            #pragma unroll
            for (int m = 0; m < 4; ++m)
                wred[wave][b * 4 + m] = l[b][m];
    __syncthreads();
    if (t < 16) {
        float s = wred[0][t] + wred[1][t] + wred[2][t] + wred[3][t];
        logits[t] = s + b2[t & 3];
    }
    __syncthreads();
    if (t < BB) {
        float v0 = logits[t * 4 + 0], v1 = logits[t * 4 + 1];
        float v2 = logits[t * 4 + 2], v3 = logits[t * 4 + 3];
        float mx = fmaxf(fmaxf(v0, v1), fmaxf(v2, v3));
        float e0 = __expf(v0 - mx), e1 = __expf(v1 - mx);
        float e2 = __expf(v2 - mx), e3 = __expf(v3 - mx);
        float denom = e0 + e1 + e2 + e3;
        strat[t * 2 + 0] = e0 / denom;
        strat[t * 2 + 1] = e1 / denom;
    }
}

// One thread per f4 of (b,h,s,d): computes BOTH k_out and v_out.
__global__ void out_kernel(const float* __restrict__ key,
                           const float* __restrict__ value,
                           const float* __restrict__ k_cache,
                           const float* __restrict__ v_cache,
                           const float* __restrict__ k_left,
                           const float* __restrict__ v_left,
                           const float* __restrict__ strat,
                           const int* __restrict__ inv,
                           float* __restrict__ out) {
    int idx = blockIdx.x * 256 + threadIdx.x;   // < 4,194,304
    int d4 = idx & 31;          // D/4 = 32
    int r  = idx >> 5;
    int s  = r & (SS - 1);
    int bh = r >> 11;           // b*KVH + h
    int b  = bh >> 3;

    float w0 = strat[b * 2 + 0];
    float wl = strat[b * 2 + 1];
    int i = inv[s];
    bool hasLeft = d4 < (RANK / 4);   // d < 64

    f4 kd, vd, kl, vl;
    kl = (f4)(0.f);
    vl = (f4)(0.f);
    if (i >= 0) {
        size_t base = ((size_t)bh * SS + i) * DD;
        kd = __builtin_nontemporal_load((const f4*)(key + base) + d4);
        vd = __builtin_nontemporal_load((const f4*)(value + base) + d4);
        if (hasLeft) { kl = kd; vl = vd; }
    } else {
        size_t cbase = ((size_t)bh * MAXSEQ + s) * DD;
        kd = *((const f4*)(k_cache + cbase) + d4);
        vd = *((const f4*)(v_cache + cbase) + d4);
        if (hasLeft) {
            size_t lbase = ((size_t)bh * MAXSEQ + s) * RANK;
            kl = *((const f4*)(k_left + lbase) + d4);
            vl = *((const f4*)(v_left + lbase) + d4);
        }
    }
    f4 ko = w0 * kd + wl * kl;
    f4 vo = w0 * vd + wl * vl;

    f4* outv = (f4*)out;
    const int KV_OFF = BB * KVH * SS * (DD / 4);   // 4,194,304
    __builtin_nontemporal_store(ko, outv + idx);
    __builtin_nontemporal_store(vo, outv + idx + KV_OFF);
}

extern "C" void kernel_launch(void* const* d_in, const int* in_sizes, int n_in,
                              void* d_out, int out_size, void* d_ws, size_t ws_size,
                              hipStream_t stream) {
    const float* hidden   = (const float*)d_in[0];
    const float* key      = (const float*)d_in[1];
    const float* value    = (const float*)d_in[2];
    const float* k_cache  = (const float*)d_in[3];
    const float* v_cache  = (const float*)d_in[4];
    const float* k_left   = (const float*)d_in[5];
    const float* v_left   = (const float*)d_in[6];
    const float* w1       = (const float*)d_in[7];
    const float* b1       = (const float*)d_in[8];
    const float* w2       = (const float*)d_in[9];
    const float* b2       = (const float*)d_in[10];
    const int*   cachepos = (const int*)d_in[11];
    const int*   layeridx = (const int*)d_in[12];
    float* out = (float*)d_out;

    float* wsf    = (float*)d_ws;
    float* pooled = wsf + WS_POOLED;
    float* hdn    = wsf + WS_HDN;
    float* strat  = wsf + WS_STRAT;
    int*   cnt    = (int*)wsf + WS_CNT;
    int*   inv    = (int*)wsf + WS_INV;

    // 1. init workspace (pooled/hdn zeros, counter 0, inv = -1)
    init_ws_kernel<<<(WS_INV + SS + 255) / 256, 256, 0, stream>>>(wsf);
    // 2. pooled partial sums (nt f4) + inverse scatter map
    pool_scatter_kernel<<<BB * 128 * 4, 256, 0, stream>>>(hidden, cachepos, pooled, inv);
    // 3. feats @ w1 (65 k-chunks) + fused mlp2 on last block
    mlp_kernel<<<65, 256, 0, stream>>>(pooled, w1, b1, w2, b2, layeridx, hdn, cnt, strat);
    // 4. fused output (nt loads/stores)
    out_kernel<<<(BB * KVH * SS * (DD / 4)) / 256, 256, 0, stream>>>(
        key, value, k_cache, v_cache, k_left, v_left, strat, inv, out);
}

// Round 6
// 95.201 us; speedup vs baseline: 1.2305x; 1.2305x over previous
//
#include <hip/hip_runtime.h>

// Problem constants (fixed by setup_inputs)
#define BB 4
#define SS 2048
#define HH 4096
#define KVH 8
#define DD 128
#define MAXSEQ 4096
#define RANK 64
#define HDN 1024   // H/4
#define NSCH 64    // s-chunks for pool partials

typedef float f4 __attribute__((ext_vector_type(4)));

// Workspace layout (float slots):
//   [0, 1048576)            parts[sch][b][c]  (64 * 4 * 4096)
//   [1048576, 1052672)      hdn (B*HDN)
//   ints at [1052672, 1054720): inv[SS]
#define WS_PARTS 0
#define WS_HDN   1048576
#define WS_INV   1052672

// ---------------- K1: pool partials (no atomics) + ws init duties ----------
// grid = 1024 blocks x 256. Block: b(4) x sch(64) x cblk(4); 32 rows x 1024 ch.
__global__ void pool_kernel(const float* __restrict__ hidden,
                            float* __restrict__ parts,
                            float* __restrict__ hdn,
                            int* __restrict__ inv) {
    const int blk = blockIdx.x, t = threadIdx.x;
    // side duties (these blocks also do pool work below)
    if (blk >= 1016) {                     // 8 blocks: inv = -1
        inv[(blk - 1016) * 256 + t] = -1;
    } else if (blk >= 1014) {              // 2 blocks: hdn = 0 (4096 floats)
        int i = (blk - 1014) * 256 + t;
        #pragma unroll
        for (int u = 0; u < 8; ++u) hdn[i * 8 + u] = 0.0f;
    }
    int b    = blk >> 8;
    int sch  = (blk >> 2) & 63;
    int cblk = blk & 3;
    int c0 = cblk * 1024 + t * 4;
    const float* base = hidden + (size_t)b * SS * HH + (size_t)sch * 32 * HH + c0;
    f4 acc = (f4)(0.f);
    #pragma unroll 8
    for (int s = 0; s < 32; ++s)
        acc += *(const f4*)(base + (size_t)s * HH);
    // parts[sch][b][c0..c0+3] — contiguous f4 store
    *(f4*)(parts + (size_t)sch * (BB * HH) + b * HH + c0) = acc;
}

// ---------------- K2: feats @ w1 -> hdn (atomics) + scatter-inv ------------
// grid = 265: blocks 0..255 = 16 w1-rows each; 256 = rows 4096..4097;
//             257..264 = scatter-inv.
__global__ void mlp1_kernel(const float* __restrict__ parts,
                            const float* __restrict__ w1,
                            const int* __restrict__ layer_idx,
                            const int* __restrict__ cache_position,
                            float* __restrict__ hdn,
                            int* __restrict__ inv) {
    const int blk = blockIdx.x, t = threadIdx.x;
    if (blk >= 257) {                      // scatter
        int i = (blk - 257) * 256 + t;
        int pos = cache_position[i];
        if (pos >= 0 && pos < SS) atomicMax(&inv[pos], i);  // last-wins
        return;
    }
    __shared__ float feats_s[16][4];
    const int k0 = blk * 16;
    const int kcnt = (blk < 256) ? 16 : 2;
    if (blk < 256) {
        // cooperative partial reduction: 64 (kk,b) pairs x 4 sub-threads
        int p = t >> 2, sub = t & 3;       // p: kk*4+b? -> kk = p>>2, b = p&3
        int kk = p >> 2, bb = p & 3;
        const float* src = parts + (size_t)(sub * 16) * (BB * HH) + bb * HH + (k0 + kk);
        float r = 0.f;
        #pragma unroll
        for (int u = 0; u < 16; ++u)
            r += src[(size_t)u * (BB * HH)];
        r += __shfl_xor(r, 1, 64);
        r += __shfl_xor(r, 2, 64);
        if (sub == 0) feats_s[kk][bb] = r * (1.0f / (float)SS);
        __syncthreads();
    }
    // GEMV: thread owns 4 consecutive j
    int j0 = t * 4;
    f4 acc[BB];
    #pragma unroll
    for (int b = 0; b < BB; ++b) acc[b] = (f4)(0.f);
    for (int kk = 0; kk < kcnt; ++kk) {
        int k = k0 + kk;
        f4 w = *(const f4*)(w1 + (size_t)k * HDN + j0);
        float f[BB];
        if (blk < 256) {
            #pragma unroll
            for (int b = 0; b < BB; ++b) f[b] = feats_s[kk][b];
        } else {
            float v = (kk == 0) ? (float)(*layer_idx) : (float)SS;
            #pragma unroll
            for (int b = 0; b < BB; ++b) f[b] = v;
        }
        #pragma unroll
        for (int b = 0; b < BB; ++b) acc[b] += f[b] * w;
    }
    #pragma unroll
    for (int b = 0; b < BB; ++b) {
        float* h = hdn + b * HDN + j0;
        atomicAdd(h + 0, acc[b].x);
        atomicAdd(h + 1, acc[b].y);
        atomicAdd(h + 2, acc[b].z);
        atomicAdd(h + 3, acc[b].w);
    }
}

// ---------------- K3: per-block mlp2 (own b only) + fused output -----------
// grid = 8192 blocks x 256 threads; idx = blk*256+t indexes f4 of k_out.
__global__ __launch_bounds__(256)
void out_kernel(const float* __restrict__ key,
                const float* __restrict__ value,
                const float* __restrict__ k_cache,
                const float* __restrict__ v_cache,
                const float* __restrict__ k_left,
                const float* __restrict__ v_left,
                const float* __restrict__ hdn,
                const float* __restrict__ b1,
                const float* __restrict__ w2,
                const float* __restrict__ b2,
                const int* __restrict__ inv,
                float* __restrict__ out) {
    const int blk = blockIdx.x, t = threadIdx.x;
    const int idx = blk * 256 + t;
    const int b = idx >> 19;               // 2^19 = KVH*SS*32 (uniform per block)

    // --- prologue: logits for this block's b, then softmax (redundant/block)
    __shared__ float wred[4][4];
    float l[4] = {0.f, 0.f, 0.f, 0.f};
    {
        int j0 = t * 4;
        f4 h4  = *(const f4*)(hdn + b * HDN + j0);
        f4 b14 = *(const f4*)(b1 + j0);
        float hv[4] = {h4.x + b14.x, h4.y + b14.y, h4.z + b14.z, h4.w + b14.w};
        #pragma unroll
        for (int jj = 0; jj < 4; ++jj) {
            float h = hv[jj] > 0.f ? hv[jj] : 0.f;
            f4 w2v = *(const f4*)(w2 + (j0 + jj) * 4);
            l[0] = fmaf(h, w2v.x, l[0]);
            l[1] = fmaf(h, w2v.y, l[1]);
            l[2] = fmaf(h, w2v.z, l[2]);
            l[3] = fmaf(h, w2v.w, l[3]);
        }
        #pragma unroll
        for (int off = 32; off > 0; off >>= 1)
            #pragma unroll
            for (int m = 0; m < 4; ++m)
                l[m] += __shfl_down(l[m], off, 64);
        int wave = t >> 6, lane = t & 63;
        if (lane == 0)
            #pragma unroll
            for (int m = 0; m < 4; ++m) wred[wave][m] = l[m];
        __syncthreads();
    }
    float lg[4];
    #pragma unroll
    for (int m = 0; m < 4; ++m)
        lg[m] = wred[0][m] + wred[1][m] + wred[2][m] + wred[3][m] + b2[m];
    float mx = fmaxf(fmaxf(lg[0], lg[1]), fmaxf(lg[2], lg[3]));
    float e0 = __expf(lg[0] - mx), e1 = __expf(lg[1] - mx);
    float e2 = __expf(lg[2] - mx), e3 = __expf(lg[3] - mx);
    float den = e0 + e1 + e2 + e3;
    float w0 = e0 / den, wl = e1 / den;

    // --- main: one f4 of k_out and one of v_out
    int d4 = idx & 31;
    int r  = idx >> 5;
    int s  = r & (SS - 1);
    int bh = r >> 11;
    int i = inv[s];
    bool hasLeft = d4 < (RANK / 4);
    f4 kd, vd, kl = (f4)(0.f), vl = (f4)(0.f);
    if (i >= 0) {
        size_t base = ((size_t)bh * SS + i) * DD;
        kd = *((const f4*)(key + base) + d4);
        vd = *((const f4*)(value + base) + d4);
        if (hasLeft) { kl = kd; vl = vd; }
    } else {
        size_t cbase = ((size_t)bh * MAXSEQ + s) * DD;
        kd = *((const f4*)(k_cache + cbase) + d4);
        vd = *((const f4*)(v_cache + cbase) + d4);
        if (hasLeft) {
            size_t lbase = ((size_t)bh * MAXSEQ + s) * RANK;
            kl = *((const f4*)(k_left + lbase) + d4);
            vl = *((const f4*)(v_left + lbase) + d4);
        }
    }
    f4 ko = w0 * kd + wl * kl;
    f4 vo = w0 * vd + wl * vl;
    f4* outv = (f4*)out;
    const int KV_OFF = BB * KVH * SS * (DD / 4);   // 2,097,152 f4
    outv[idx] = ko;
    outv[idx + KV_OFF] = vo;
}

extern "C" void kernel_launch(void* const* d_in, const int* in_sizes, int n_in,
                              void* d_out, int out_size, void* d_ws, size_t ws_size,
                              hipStream_t stream) {
    const float* hidden   = (const float*)d_in[0];
    const float* key      = (const float*)d_in[1];
    const float* value    = (const float*)d_in[2];
    const float* k_cache  = (const float*)d_in[3];
    const float* v_cache  = (const float*)d_in[4];
    const float* k_left   = (const float*)d_in[5];
    const float* v_left   = (const float*)d_in[6];
    const float* w1       = (const float*)d_in[7];
    const float* b1       = (const float*)d_in[8];
    const float* w2       = (const float*)d_in[9];
    const float* b2       = (const float*)d_in[10];
    const int*   cachepos = (const int*)d_in[11];
    const int*   layeridx = (const int*)d_in[12];
    float* out = (float*)d_out;

    float* wsf   = (float*)d_ws;
    float* parts = wsf + WS_PARTS;
    float* hdn   = wsf + WS_HDN;
    int*   inv   = (int*)wsf + WS_INV;

    // K1: pool partials + inv=-1 + hdn=0
    pool_kernel<<<1024, 256, 0, stream>>>(hidden, parts, hdn, inv);
    // K2: reduce partials -> feats; GEMV w1 -> hdn; scatter-inv
    mlp1_kernel<<<265, 256, 0, stream>>>(parts, w1, layeridx, cachepos, hdn, inv);
    // K3: per-block mlp2 + fused output
    out_kernel<<<BB * KVH * SS * (DD / 4) / 256, 256, 0, stream>>>(
        key, value, k_cache, v_cache, k_left, v_left,
        hdn, b1, w2, b2, inv, out);
}